// Round 2
// baseline (557.835 us; speedup 1.0000x reference)
//
#include <hip/hip_runtime.h>

#define HID   100
#define GATES 400
#define INP   4
#define TMAX  256
#define SB    16      // sequences per block (one MFMA M-tile)
#define ULD   136     // u_lds row stride in halves (272 B, 16B-aligned)
#define NTH   512     // 8 waves

typedef _Float16 half8 __attribute__((ext_vector_type(8)));
typedef float    f32x4 __attribute__((ext_vector_type(4)));

__device__ __forceinline__ float fexp2(float x) { return __builtin_amdgcn_exp2f(x); }
__device__ __forceinline__ float frcp(float x)  { return __builtin_amdgcn_rcpf(x); }
__device__ __forceinline__ float sigm(float x)  { return frcp(1.f + fexp2(-1.44269504f * x)); }
__device__ __forceinline__ float tanh_f(float x){ return 1.f - 2.f * frcp(1.f + fexp2(2.88539008f * x)); }

// quad-perm DPP lane exchange (free, VALU pipe, no LDS)
template<int CTRL>
__device__ __forceinline__ float dppf(float v) {
    int i = __builtin_bit_cast(int, v);
    i = __builtin_amdgcn_mov_dpp(i, CTRL, 0xF, 0xF, true);
    return __builtin_bit_cast(float, i);
}
#define XOR1 0xB1   // quad_perm [1,0,3,2]
#define XOR2 0x4E   // quad_perm [2,3,0,1]

__global__ __launch_bounds__(NTH) void lstm_persist(
    const float* __restrict__ xg,     // [N][T][4]
    const float* __restrict__ w_ih,   // [400][4]
    const float* __restrict__ w_hh,   // [400][100]
    const float* __restrict__ b_ih,   // [400]
    const float* __restrict__ b_hh,   // [400]
    const int*   __restrict__ lens,   // [N]
    float* __restrict__ out)          // [N][100]
{
    __shared__ _Float16 u_lds[2][SB * ULD];   // double-buffered [seq][136]: h | x | 1 | pad
    __shared__ int len_s[SB];
    __shared__ int maxlen_s;

    const int tid  = threadIdx.x;
    const int wave = tid >> 6;
    const int lane = tid & 63;
    const int l15  = lane & 15;
    const int l4   = lane >> 4;
    const int ty   = l15 & 3;      // gate type slot within quad: 0=i 1=f 2=g 3=o
    const int ul   = l15 >> 2;     // unit-within-tile
    const int seq0 = blockIdx.x * SB;

    if (tid < SB) len_s[tid] = lens[seq0 + tid];
    {   // zero both buffers; bias column (k==104) = 1.0
        _Float16* u0 = &u_lds[0][0];
        for (int i = tid; i < 2 * SB * ULD; i += NTH) {
            int col = i % ULD;
            u0[i] = (col == (HID + INP)) ? (_Float16)1.f : (_Float16)0.f;
        }
    }

    // ---- B fragments (weights) in registers, INTERLEAVED gate layout:
    // output position p = 4*unit + ty  ->  original gate row = ty*100 + unit
    half8 bfrag[4][4];
    int   tn[4];
    #pragma unroll
    for (int i = 0; i < 4; ++i) {
        int n = wave + 8 * i;
        tn[i] = n;
        if (n < 25) {
            int p = n * 16 + l15;
            int grow = (p & 3) * HID + (p >> 2);
            #pragma unroll
            for (int c = 0; c < 4; ++c) {
                half8 v;
                #pragma unroll
                for (int j = 0; j < 8; ++j) {
                    int k = c * 32 + l4 * 8 + j;
                    float w;
                    if (k < HID)             w = w_hh[grow * HID + k];
                    else if (k < HID + INP)  w = w_ih[grow * INP + (k - HID)];
                    else if (k == HID + INP) w = b_ih[grow] + b_hh[grow];
                    else                     w = 0.f;
                    v[j] = (_Float16)w;
                }
                bfrag[i][c] = v;
            }
        }
    }

    __syncthreads();

    if (tid == 0) {
        int m = 0;
        for (int s = 0; s < SB; ++s) m = m > len_s[s] ? m : len_s[s];
        maxlen_s = m;
    }
    int lenr[4];
    #pragma unroll
    for (int r = 0; r < 4; ++r) lenr[r] = len_s[l4 * 4 + r];

    // x(0) into buf0; register-prefetch x(1), x(2)
    float xv1 = 0.f, xv2 = 0.f;
    if (tid < 64) {
        int s = tid >> 2, c = tid & 3;
        const float* xs = xg + (size_t)(seq0 + s) * TMAX * INP + c;
        u_lds[0][s * ULD + HID + c] = (_Float16)xs[0];
        xv1 = xs[1 * INP];
        xv2 = xs[2 * INP];
    }

    float creg[4][4] = {};   // c-state, replicated on ty0/ty1 lanes, per (tile, r)
    __syncthreads();
    const int maxlen = maxlen_s;

    const _Float16* ab0 = &u_lds[0][l15 * ULD + l4 * 8];
    const _Float16* ab1 = &u_lds[1][l15 * ULD + l4 * 8];

    for (int t = 0; t < maxlen; ++t) {
        const _Float16* abase = (t & 1) ? ab1 : ab0;
        _Float16* ubn = (t & 1) ? &u_lds[0][0] : &u_lds[1][0];

        half8 afr[4];
        #pragma unroll
        for (int c = 0; c < 4; ++c)
            afr[c] = *(const half8*)(abase + c * 32);

        // stage x(t+1) into next buffer; issue load of x(t+3)
        if (tid < 64) {
            int s = tid >> 2, c = tid & 3;
            if (t + 1 < TMAX) ubn[s * ULD + HID + c] = (_Float16)xv1;
            xv1 = xv2;
            int tt = t + 3;
            xv2 = (tt < TMAX) ? xg[((size_t)(seq0 + s) * TMAX + tt) * INP + c] : 0.f;
        }

        #pragma unroll
        for (int i = 0; i < 4; ++i) {
            if (tn[i] < 25) {
                f32x4 acc = {0.f, 0.f, 0.f, 0.f};
                #pragma unroll
                for (int c = 0; c < 4; ++c)
                    acc = __builtin_amdgcn_mfma_f32_16x16x32_f16(afr[c], bfrag[i][c], acc, 0, 0, 0);
                // D: col(p) = l15, row(seq) = l4*4 + r
                #pragma unroll
                for (int r = 0; r < 4; ++r) {
                    float v = acc[r];
                    float a = (ty == 2) ? tanh_f(v) : sigm(v);
                    float b = dppf<XOR2>(a);               // ty0<-g, ty1<-o
                    float prod = (ty == 1) ? a * creg[i][r] : a * b;   // ty0:i*g, ty1:f*c
                    float q = dppf<XOR1>(prod);            // exchange i*g <-> f*c
                    float cn = prod + q;
                    bool live = t < lenr[r];
                    if (ty <= 1 && live) creg[i][r] = cn;  // c replicated on ty0,ty1
                    if (ty == 1 && live) {
                        float hn = b * tanh_f(cn);         // b = o
                        int seq = l4 * 4 + r;
                        int u = tn[i] * 4 + ul;
                        ubn[seq * ULD + u] = (_Float16)hn;
                        if (t == lenr[r] - 1)
                            out[(size_t)(seq0 + seq) * HID + u] = hn;
                    }
                }
            }
        }
        __syncthreads();   // ONE barrier per step
    }
}

extern "C" void kernel_launch(void* const* d_in, const int* in_sizes, int n_in,
                              void* d_out, int out_size, void* d_ws, size_t ws_size,
                              hipStream_t stream) {
    const float* xg   = (const float*)d_in[0];
    const float* w_ih = (const float*)d_in[1];
    const float* w_hh = (const float*)d_in[2];
    const float* b_ih = (const float*)d_in[3];
    const float* b_hh = (const float*)d_in[4];
    const int*   lens = (const int*)d_in[5];
    float* out = (float*)d_out;
    const int N = in_sizes[5];           // 4096
    lstm_persist<<<dim3(N / SB), NTH, 0, stream>>>(xg, w_ih, w_hh, b_ih, b_hh, lens, out);
}

// Round 3
// 321.313 us; speedup vs baseline: 1.7361x; 1.7361x over previous
//
#include <hip/hip_runtime.h>

#define HID    100
#define GATES  400
#define INP    4
#define TMAX   256
#define SB     8      // sequences per block (half of MFMA M=16; waste M for 2 blocks/CU)
#define ULD    136    // u_lds row stride in halves (272 B, 16B-aligned)
#define GLD    404    // g_lds row stride in f32 words (1616 B, 16B-aligned, conflict-free stores)
#define NTH    256    // 4 waves
#define NTILES 25
#define TPW    7      // max tiles per wave (4 waves x 7 >= 25)

typedef _Float16 half8 __attribute__((ext_vector_type(8)));
typedef float    f32x4 __attribute__((ext_vector_type(4)));

__device__ __forceinline__ float fexp2(float x) { return __builtin_amdgcn_exp2f(x); }
__device__ __forceinline__ float frcp(float x)  { return __builtin_amdgcn_rcpf(x); }
__device__ __forceinline__ float sigm(float x)  { return frcp(1.f + fexp2(-1.44269504f * x)); }
__device__ __forceinline__ float tanh_f(float x){ return 1.f - 2.f * frcp(1.f + fexp2(2.88539008f * x)); }

__global__ __launch_bounds__(NTH, 2) void lstm_persist(
    const float* __restrict__ xg,     // [N][T][4]
    const float* __restrict__ w_ih,   // [400][4]
    const float* __restrict__ w_hh,   // [400][100]
    const float* __restrict__ b_ih,   // [400]
    const float* __restrict__ b_hh,   // [400]
    const int*   __restrict__ lens,   // [N]
    float* __restrict__ out)          // [N][100]
{
    __shared__ _Float16 u_lds[2][16 * ULD];   // 16 A-rows; rows 8..15 stay zero (h|x|1|pad)
    __shared__ float    g_lds[SB * GLD];      // interleaved gates: [seq][4*unit + ty]
    __shared__ int      len_s[SB];
    __shared__ int      maxlen_s;

    const int tid  = threadIdx.x;
    const int wave = tid >> 6;
    const int lane = tid & 63;
    const int l15  = lane & 15;
    const int l4   = lane >> 4;
    const int seq0 = blockIdx.x * SB;

    if (tid < SB) len_s[tid] = lens[seq0 + tid];
    {   // zero both A-buffers; bias column (k==104) = 1.0
        _Float16* u0 = &u_lds[0][0];
        for (int i = tid; i < 2 * 16 * ULD; i += NTH) {
            int col = i % ULD;
            u0[i] = (col == (HID + INP)) ? (_Float16)1.f : (_Float16)0.f;
        }
    }

    // ---- B fragments resident in registers, interleaved output layout:
    // output position p = 4*unit + ty  ->  original gate row = ty*100 + unit
    // Wave w owns tiles w, w+4, ..., w+24 (7 for wave 0, 6 for waves 1-3).
    half8 bfrag[TPW][4];
    int   tn[TPW];
    #pragma unroll
    for (int i = 0; i < TPW; ++i) {
        int n = wave + 4 * i;
        tn[i] = n;
        if (n < NTILES) {
            int p = n * 16 + l15;
            int grow = (p & 3) * HID + (p >> 2);
            #pragma unroll
            for (int c = 0; c < 4; ++c) {
                half8 v;
                #pragma unroll
                for (int j = 0; j < 8; ++j) {
                    int k = c * 32 + l4 * 8 + j;
                    float w;
                    if (k < HID)             w = w_hh[grow * HID + k];
                    else if (k < HID + INP)  w = w_ih[grow * INP + (k - HID)];
                    else if (k == HID + INP) w = b_ih[grow] + b_hh[grow];
                    else                     w = 0.f;
                    v[j] = (_Float16)w;
                }
                bfrag[i][c] = v;
            }
        }
    }

    __syncthreads();
    if (tid == 0) {
        int m = 0;
        for (int s = 0; s < SB; ++s) m = m > len_s[s] ? m : len_s[s];
        maxlen_s = m;
    }

    // update-phase items: 800 = 8 seq x 100 units over 256 threads (up to 4 each)
    int iseq[4], iunit[4], ilen[4];
    float creg[4] = {};
    #pragma unroll
    for (int ii = 0; ii < 4; ++ii) {
        int item = tid + NTH * ii;
        if (item < SB * HID) { iseq[ii] = item / HID; iunit[ii] = item % HID; }
        else                 { iseq[ii] = 0;          iunit[ii] = 0; }
    }

    // x(0) into buf0; register-prefetch x(1), x(2)
    float xv1 = 0.f, xv2 = 0.f;
    if (tid < SB * INP) {
        int s = tid >> 2, c = tid & 3;
        const float* xs = xg + (size_t)(seq0 + s) * TMAX * INP + c;
        u_lds[0][s * ULD + HID + c] = (_Float16)xs[0];
        xv1 = xs[INP];
        xv2 = xs[2 * INP];
    }
    __syncthreads();
    #pragma unroll
    for (int ii = 0; ii < 4; ++ii)
        ilen[ii] = (tid + NTH * ii < SB * HID) ? len_s[iseq[ii]] : 0;

    const int maxlen = maxlen_s;
    const _Float16* ab0 = &u_lds[0][l15 * ULD + l4 * 8];
    const _Float16* ab1 = &u_lds[1][l15 * ULD + l4 * 8];

    for (int t = 0; t < maxlen; ++t) {
        const _Float16* abase = (t & 1) ? ab1 : ab0;
        _Float16* ubn = (t & 1) ? &u_lds[0][0] : &u_lds[1][0];

        half8 afr[4];
        #pragma unroll
        for (int c = 0; c < 4; ++c)
            afr[c] = *(const half8*)(abase + c * 32);

        // stage x(t+1) into next buffer; issue load of x(t+3)
        if (tid < SB * INP) {
            int s = tid >> 2, c = tid & 3;
            ubn[s * ULD + HID + c] = (_Float16)xv1;
            xv1 = xv2;
            int tt = t + 3;
            xv2 = (tt < TMAX) ? xg[((size_t)(seq0 + s) * TMAX + tt) * INP + c] : 0.f;
        }

        // ---- MFMA: gates[16][400], store only real rows (l4 < 2 -> seqs 0..7)
        #pragma unroll
        for (int i = 0; i < TPW; ++i) {
            if (tn[i] < NTILES) {
                f32x4 acc = {0.f, 0.f, 0.f, 0.f};
                #pragma unroll
                for (int c = 0; c < 4; ++c)
                    acc = __builtin_amdgcn_mfma_f32_16x16x32_f16(afr[c], bfrag[i][c], acc, 0, 0, 0);
                if (l4 < 2) {
                    int base = tn[i] * 16 + l15;
                    #pragma unroll
                    for (int r = 0; r < 4; ++r)
                        g_lds[(l4 * 4 + r) * GLD + base] = acc[r];
                }
            }
        }
        __syncthreads();

        // ---- distributed elementwise update; one b128 read gets all 4 gates
        #pragma unroll
        for (int ii = 0; ii < 4; ++ii) {
            if (t < ilen[ii]) {
                f32x4 g4 = *(const f32x4*)&g_lds[iseq[ii] * GLD + 4 * iunit[ii]];
                float i_ = sigm(g4.x);
                float f_ = sigm(g4.y);
                float gg = tanh_f(g4.z);
                float o_ = sigm(g4.w);
                float cn = f_ * creg[ii] + i_ * gg;
                float hn = o_ * tanh_f(cn);
                creg[ii] = cn;
                ubn[iseq[ii] * ULD + iunit[ii]] = (_Float16)hn;
                if (t == ilen[ii] - 1)
                    out[(size_t)(seq0 + iseq[ii]) * HID + iunit[ii]] = hn;
            }
        }
        __syncthreads();
    }
}

extern "C" void kernel_launch(void* const* d_in, const int* in_sizes, int n_in,
                              void* d_out, int out_size, void* d_ws, size_t ws_size,
                              hipStream_t stream) {
    const float* xg   = (const float*)d_in[0];
    const float* w_ih = (const float*)d_in[1];
    const float* w_hh = (const float*)d_in[2];
    const float* b_ih = (const float*)d_in[3];
    const float* b_hh = (const float*)d_in[4];
    const int*   lens = (const int*)d_in[5];
    float* out = (float*)d_out;
    const int N = in_sizes[5];           // 4096
    lstm_persist<<<dim3(N / SB), NTH, 0, stream>>>(xg, w_ih, w_hh, b_ih, b_hh, lens, out);
}

// Round 4
// 207.706 us; speedup vs baseline: 2.6857x; 1.5470x over previous
//
#include <hip/hip_runtime.h>

#define HID    100
#define GATES  400
#define INP    4
#define TMAX   256
#define SB     16     // sequences per block = full MFMA M
#define ULD    136    // u_lds row stride in halves (272 B = 17*16, 16B-aligned)
#define NTH    512    // 8 waves
#define NTILES 25

typedef _Float16 half8 __attribute__((ext_vector_type(8)));
typedef float    f32x4 __attribute__((ext_vector_type(4)));

__device__ __forceinline__ float fexp2(float x) { return __builtin_amdgcn_exp2f(x); }
__device__ __forceinline__ float frcp(float x)  { return __builtin_amdgcn_rcpf(x); }
__device__ __forceinline__ float sigm(float x)  { return frcp(1.f + fexp2(-1.44269504f * x)); }
__device__ __forceinline__ float tanh_f(float x){ return 1.f - 2.f * frcp(1.f + fexp2(2.88539008f * x)); }

__global__ __launch_bounds__(NTH) void lstm_persist(
    const float* __restrict__ xg,     // [N][T][4]
    const float* __restrict__ w_ih,   // [400][4]
    const float* __restrict__ w_hh,   // [400][100]
    const float* __restrict__ b_ih,   // [400]
    const float* __restrict__ b_hh,   // [400]
    const int*   __restrict__ lens,   // [N]
    float* __restrict__ out)          // [N][100]
{
    __shared__ _Float16 u_lds[2][SB * ULD];   // double-buffered [seq][136]: h[0..99] | x[100..103] | 1 | 0-pad
    __shared__ int len_s[SB];
    __shared__ int maxlen_s;

    const int tid  = threadIdx.x;
    const int wave = tid >> 6;
    const int lane = tid & 63;
    const int l15  = lane & 15;    // = seq (B-col and D-col)
    const int l4   = lane >> 4;
    const int seq0 = blockIdx.x * SB;

    if (tid < SB) len_s[tid] = lens[seq0 + tid];
    {   // zero both buffers; bias column (k==104) = 1.0
        _Float16* u0 = &u_lds[0][0];
        for (int i = tid; i < 2 * SB * ULD; i += NTH) {
            int col = i % ULD;
            u0[i] = (col == (HID + INP)) ? (_Float16)1.f : (_Float16)0.f;
        }
    }

    // ---- Weights as A-operand fragments, register-resident.
    // Wave w owns tiles w, w+8, w+16 (+24 for wave 0): 25 total.
    // Tile n covers output positions p = n*16 + m (m = A-row = l15 in frag).
    // Interleaved layout: p = 4*unit + ty  ->  original gate row = ty*100 + unit.
    half8 afrag[4][4];
    int   tn[4];
    #pragma unroll
    for (int i = 0; i < 4; ++i) {
        int n = wave + 8 * i;
        tn[i] = n;
        if (n < NTILES) {
            int p = n * 16 + l15;                    // A-row index = l15
            int grow = (p & 3) * HID + (p >> 2);     // ty*100 + unit
            #pragma unroll
            for (int c = 0; c < 4; ++c) {
                half8 v;
                #pragma unroll
                for (int j = 0; j < 8; ++j) {
                    int k = c * 32 + l4 * 8 + j;
                    float w;
                    if (k < HID)             w = w_hh[grow * HID + k];
                    else if (k < HID + INP)  w = w_ih[grow * INP + (k - HID)];
                    else if (k == HID + INP) w = b_ih[grow] + b_hh[grow];
                    else                     w = 0.f;
                    v[j] = (_Float16)w;
                }
                afrag[i][c] = v;
            }
        }
    }

    __syncthreads();
    if (tid == 0) {
        int m = 0;
        for (int s = 0; s < SB; ++s) m = m > len_s[s] ? m : len_s[s];
        maxlen_s = m;
    }

    // x(0) into buf0; register-prefetch x(1), x(2). Wave 7 (3 tiles) does x-duty.
    float xv1 = 0.f, xv2 = 0.f;
    if (tid >= NTH - 64) {
        int idx = tid - (NTH - 64);
        int s = idx >> 2, ch = idx & 3;
        const float* xs = xg + (size_t)(seq0 + s) * TMAX * INP + ch;
        u_lds[0][s * ULD + HID + ch] = (_Float16)xs[0];
        xv1 = xs[INP];
        xv2 = xs[2 * INP];
    }
    float creg[4] = {};           // c-state: one per owned tile, lane-local
    __syncthreads();

    const int maxlen = maxlen_s;
    const int mylen  = len_s[l15];
    const _Float16* ub0 = &u_lds[0][l15 * ULD + l4 * 8];
    const _Float16* ub1 = &u_lds[1][l15 * ULD + l4 * 8];

    for (int t = 0; t < maxlen; ++t) {
        const _Float16* ub = (t & 1) ? ub1 : ub0;
        _Float16* ubn = (t & 1) ? &u_lds[0][0] : &u_lds[1][0];

        // B-fragments: u for this step (col = l15 = seq, k = c*32 + l4*8 + j)
        half8 bfr[4];
        #pragma unroll
        for (int c = 0; c < 4; ++c)
            bfr[c] = *(const half8*)(ub + c * 32);

        // stage x(t+1) into next buffer; issue load of x(t+3)
        if (tid >= NTH - 64) {
            int idx = tid - (NTH - 64);
            int s = idx >> 2, ch = idx & 3;
            ubn[s * ULD + HID + ch] = (_Float16)xv1;
            xv1 = xv2;
            int tt = t + 3;
            xv2 = (tt < TMAX) ? xg[((size_t)(seq0 + s) * TMAX + tt) * INP + ch] : 0.f;
        }

        #pragma unroll
        for (int i = 0; i < 4; ++i) {
            if (tn[i] < NTILES) {
                f32x4 acc = {0.f, 0.f, 0.f, 0.f};
                #pragma unroll
                for (int c = 0; c < 4; ++c)
                    acc = __builtin_amdgcn_mfma_f32_16x16x32_f16(afrag[i][c], bfr[c], acc, 0, 0, 0);
                // Lane (l15,l4) holds i,f,g,o for (seq=l15, unit=tn[i]*4+l4)
                if (t < mylen) {
                    float i_ = sigm(acc[0]);
                    float f_ = sigm(acc[1]);
                    float g_ = tanh_f(acc[2]);
                    float o_ = sigm(acc[3]);
                    float cn = f_ * creg[i] + i_ * g_;
                    float hn = o_ * tanh_f(cn);
                    creg[i] = cn;
                    int unit = tn[i] * 4 + l4;
                    ubn[l15 * ULD + unit] = (_Float16)hn;
                    if (t == mylen - 1)
                        out[(size_t)(seq0 + l15) * HID + unit] = hn;
                }
            }
        }
        __syncthreads();   // one barrier per step
    }
}

extern "C" void kernel_launch(void* const* d_in, const int* in_sizes, int n_in,
                              void* d_out, int out_size, void* d_ws, size_t ws_size,
                              hipStream_t stream) {
    const float* xg   = (const float*)d_in[0];
    const float* w_ih = (const float*)d_in[1];
    const float* w_hh = (const float*)d_in[2];
    const float* b_ih = (const float*)d_in[3];
    const float* b_hh = (const float*)d_in[4];
    const int*   lens = (const int*)d_in[5];
    float* out = (float*)d_out;
    const int N = in_sizes[5];           // 4096
    lstm_persist<<<dim3(N / SB), NTH, 0, stream>>>(xg, w_ih, w_hh, b_ih, b_hh, lens, out);
}

// Round 5
// 167.214 us; speedup vs baseline: 3.3361x; 1.2422x over previous
//
#include <hip/hip_runtime.h>

#define HID    100
#define GATES  400
#define INP    4
#define TMAX   256
#define SB     16     // sequences per block = full MFMA M/N
#define ULD    136    // u_lds row stride in halves (272 B = 17*16, 16B-aligned)
#define NTH    1024   // 16 waves -> 4 waves/SIMD
#define NTILES 25

typedef _Float16 half8 __attribute__((ext_vector_type(8)));
typedef float    f32x4 __attribute__((ext_vector_type(4)));

#define L2E  1.442695040888963f
#define L2E2 2.885390081777927f

__device__ __forceinline__ float fexp2(float x) { return __builtin_amdgcn_exp2f(x); }
__device__ __forceinline__ float frcp(float x)  { return __builtin_amdgcn_rcpf(x); }

__global__ __launch_bounds__(NTH) void lstm_persist(
    const float* __restrict__ xg,     // [N][T][4]
    const float* __restrict__ w_ih,   // [400][4]
    const float* __restrict__ w_hh,   // [400][100]
    const float* __restrict__ b_ih,   // [400]
    const float* __restrict__ b_hh,   // [400]
    const int*   __restrict__ lens,   // [N]
    float* __restrict__ out)          // [N][100]
{
    __shared__ _Float16 u_lds[2][SB * ULD];   // dbuf [seq][136]: h[0..99] | x[100..103] | 1 | 0-pad
    __shared__ int len_s[SB];
    __shared__ int maxlen_s;

    const int tid  = threadIdx.x;
    const int wave = tid >> 6;
    const int lane = tid & 63;
    const int l15  = lane & 15;    // seq (B-col = D-col)
    const int l4   = lane >> 4;
    const int seq0 = blockIdx.x * SB;

    if (tid < SB) len_s[tid] = lens[seq0 + tid];
    {   // zero both buffers; bias column (k==104) = 1.0
        _Float16* u0 = &u_lds[0][0];
        for (int i = tid; i < 2 * SB * ULD; i += NTH) {
            int col = i % ULD;
            u0[i] = (col == (HID + INP)) ? (_Float16)1.f : (_Float16)0.f;
        }
    }

    // ---- Weights as A-operand fragments, register-resident, PRESCALED.
    // Wave w owns tile w (and w+16 if < 25).
    // Position p = n*16 + l4*4 + r ; ty = p&3 (0=i,1=f,2=g,3=o);
    // q = p>>2 ; unit = 25*(q&3) + (q>>2)  (write-conflict-free remap).
    // Row scale: i,f,o -> -log2(e) ; g -> +2*log2(e)  (folded into weights+bias).
    half8 afrag[2][4];
    int   tn[2];
    tn[0] = wave;
    tn[1] = (wave + 16 < NTILES) ? wave + 16 : NTILES;
    #pragma unroll
    for (int i = 0; i < 2; ++i) {
        int n = tn[i];
        if (n < NTILES) {
            int p  = n * 16 + l15;                 // A-row = l15
            int ty = p & 3;
            int q  = p >> 2;
            int unit = 25 * (q & 3) + (q >> 2);
            int grow = ty * HID + unit;
            float scale = (ty == 2) ? L2E2 : -L2E;
            #pragma unroll
            for (int c = 0; c < 4; ++c) {
                half8 v;
                #pragma unroll
                for (int j = 0; j < 8; ++j) {
                    int k = c * 32 + l4 * 8 + j;
                    float w;
                    if (k < HID)             w = w_hh[grow * HID + k];
                    else if (k < HID + INP)  w = w_ih[grow * INP + (k - HID)];
                    else if (k == HID + INP) w = b_ih[grow] + b_hh[grow];
                    else                     w = 0.f;
                    v[j] = (_Float16)(scale * w);
                }
                afrag[i][c] = v;
            }
        }
    }

    __syncthreads();
    if (tid == 0) {
        int m = 0;
        for (int s = 0; s < SB; ++s) m = m > len_s[s] ? m : len_s[s];
        maxlen_s = m;
    }

    // x(0) into buf0; register-prefetch x(1), x(2). Wave 15 (1 tile) does x-duty.
    float xv1 = 0.f, xv2 = 0.f;
    if (tid >= NTH - 64) {
        int idx = tid - (NTH - 64);
        int s = idx >> 2, ch = idx & 3;
        const float* xs = xg + (size_t)(seq0 + s) * TMAX * INP + ch;
        u_lds[0][s * ULD + HID + ch] = (_Float16)xs[0];
        xv1 = xs[INP];
        xv2 = xs[2 * INP];
    }
    float creg[2] = {};
    __syncthreads();

    const int maxlen = maxlen_s;
    const int mylen  = len_s[l15];
    const _Float16* ub0 = &u_lds[0][l15 * ULD + l4 * 8];
    const _Float16* ub1 = &u_lds[1][l15 * ULD + l4 * 8];

    for (int t = 0; t < maxlen; ++t) {
        const _Float16* ub = (t & 1) ? ub1 : ub0;
        _Float16* ubn = (t & 1) ? &u_lds[0][0] : &u_lds[1][0];

        // B-fragments: u for this step (col = l15 = seq, k = c*32 + l4*8 + j)
        half8 bfr[4];
        #pragma unroll
        for (int c = 0; c < 4; ++c)
            bfr[c] = *(const half8*)(ub + c * 32);

        // stage x(t+1) into next buffer; issue load of x(t+3)
        if (tid >= NTH - 64) {
            int idx = tid - (NTH - 64);
            int s = idx >> 2, ch = idx & 3;
            ubn[s * ULD + HID + ch] = (_Float16)xv1;
            xv1 = xv2;
            int tt = t + 3;
            xv2 = (tt < TMAX) ? xg[((size_t)(seq0 + s) * TMAX + tt) * INP + ch] : 0.f;
        }

        #pragma unroll
        for (int i = 0; i < 2; ++i) {
            if (tn[i] < NTILES) {
                f32x4 acc = {0.f, 0.f, 0.f, 0.f};
                #pragma unroll
                for (int c = 0; c < 4; ++c)
                    acc = __builtin_amdgcn_mfma_f32_16x16x32_f16(afrag[i][c], bfr[c], acc, 0, 0, 0);
                // acc[r] = prescaled preactivation; r: 0=i 1=f 2=g 3=o
                // lane (l15,l4): seq = l15, unit = 25*l4 + tn[i]
                if (t < mylen) {
                    float e_i = fexp2(acc[0]);            // exp(-z_i)
                    float e_f = fexp2(acc[1]);            // exp(-z_f)
                    float e_g = fexp2(acc[2]);            // exp(+2 z_g)
                    float e_o = fexp2(acc[3]);            // exp(-z_o)
                    float tg  = 1.f + e_g;
                    float d1  = __builtin_fmaf(e_i, tg, tg);     // (1+e_i)(1+e_g)
                    float r1  = frcp(d1);
                    float ig  = __builtin_fmaf(e_g, r1, -r1);    // i*g
                    float r2  = frcp(1.f + e_f);                 // f
                    float cn  = __builtin_fmaf(r2, creg[i], ig);
                    float tc  = fminf(L2E2 * cn, 60.f);
                    float e_c = fexp2(tc);                       // exp(+2 cn), clamped
                    float t3  = 1.f + e_c;
                    float d3  = __builtin_fmaf(e_o, t3, t3);     // (1+e_o)(1+e_c)
                    float r3  = frcp(d3);
                    float hn  = __builtin_fmaf(e_c, r3, -r3);    // o*tanh(cn)
                    creg[i] = cn;
                    int unit = 25 * l4 + tn[i];
                    ubn[l15 * ULD + unit] = (_Float16)hn;
                    if (t == mylen - 1)
                        out[(size_t)(seq0 + l15) * HID + unit] = hn;
                }
            }
        }
        __syncthreads();   // one barrier per step
    }
}

extern "C" void kernel_launch(void* const* d_in, const int* in_sizes, int n_in,
                              void* d_out, int out_size, void* d_ws, size_t ws_size,
                              hipStream_t stream) {
    const float* xg   = (const float*)d_in[0];
    const float* w_ih = (const float*)d_in[1];
    const float* w_hh = (const float*)d_in[2];
    const float* b_ih = (const float*)d_in[3];
    const float* b_hh = (const float*)d_in[4];
    const int*   lens = (const int*)d_in[5];
    float* out = (float*)d_out;
    const int N = in_sizes[5];           // 4096
    lstm_persist<<<dim3(N / SB), NTH, 0, stream>>>(xg, w_ih, w_hh, b_ih, b_hh, lens, out);
}